// Round 13
// baseline (175.505 us; speedup 1.0000x reference)
//
#include <hip/hip_runtime.h>
#include <cfloat>
#include <math.h>

// GATConv fused pipeline for MI355X.
// inputs: row[E] i32, col[E] i32, h[N,256] f32, W[256,128] f32, a_l[8,16] f32, a_r[8,16] f32
// output: relu(h_prime) [N,16,8] f32.
//
// R13:
//  prepack    : W -> MFMA B-fragments + cursor inits.
//  gemm_push  : fused dispatch. Blocks [0,NGEMM): MFMA bf16 gemm, full A preload
//               (R12 proven). Blocks [NGEMM,+NPUSH): push1 LDS tile-reorder radix
//               scatter to 196 coarse buckets (dense burst writes) -- overlaps
//               with the latency-bound gemm.
//  push2      : coarse slab -> 8 fine slabs (dense both sides).
//  bucket_gat : R9 structure, phase B processes ROW PAIRS concurrently (2x MLP
//               on the L3-latency-bound Whb gather; R12 counters: 196MB TCC @
//               2.7 TB/s, VALU 43% -> latency-bound, not BW-bound).

constexpr int IN_F  = 256;
constexpr int F     = 128;   // OUT*HEADS
constexpr int HEADS = 8;
constexpr int BS    = 32;    // rows per fine bucket
constexpr int BSH   = 5;
constexpr int SLAB  = 2048;  // fine slab capacity (avg 1024, ~32 sigma)
constexpr int CSLAB = 9216;  // coarse slab capacity (avg 8192, ~11 sigma)
constexpr int PTILE = 4096;  // push1 tile size

typedef __attribute__((ext_vector_type(8))) short bf16x8;  // 8 bf16 in 4 VGPRs
typedef __attribute__((ext_vector_type(4))) float f32x4;

__device__ inline uint f2bf(float x) {              // f32 -> bf16 RNE (upper 16 bits)
    uint u = __float_as_uint(x);
    return (u + 0x7fffu + ((u >> 16) & 1u)) >> 16;
}
__device__ inline uint pack2(float a, float b) { return f2bf(a) | (f2bf(b) << 16); }

// ---------------- W prepack + cursor inits --------------------------------------
__global__ __launch_bounds__(256) void prepack(const float* __restrict__ W,
                                               uint4* __restrict__ Wf,
                                               int* __restrict__ cursorC,
                                               int* __restrict__ cursorF,
                                               int NC, int NBF)
{
    if (blockIdx.x == 0) {
        for (int i = threadIdx.x; i < NC; i += 256) cursorC[i] = i * CSLAB;
        for (int i = threadIdx.x; i < NBF; i += 256) cursorF[i] = i * SLAB;
    }
    int t = blockIdx.x * 256 + threadIdx.x;
    if (t >= 8 * 8 * 64) return;
    int ks = t >> 9, nt = (t >> 6) & 7, l = t & 63;
    int col = nt * 16 + (l & 15);
    int k0 = ks * 32 + (l >> 4) * 8;
    float v[8];
#pragma unroll
    for (int i = 0; i < 8; ++i) v[i] = W[(size_t)(k0 + i) * F + col];
    Wf[t] = make_uint4(pack2(v[0], v[1]), pack2(v[2], v[3]),
                       pack2(v[4], v[5]), pack2(v[6], v[7]));
}

// ---------------- fused: MFMA GEMM (blocks < NGEMM) + push1 (rest) --------------
__global__ __launch_bounds__(256) void gemm_push(
    const float* __restrict__ h, const uint4* __restrict__ Wf,
    const float* __restrict__ a_l, const float* __restrict__ a_r,
    uint* __restrict__ Whb, float* __restrict__ Wh1, float* __restrict__ Wh2,
    int n, int NGEMM,
    const int* __restrict__ row, const int* __restrict__ col,
    int* __restrict__ cursorC, uint* __restrict__ cpairs, int E)
{
    __shared__ uint stage[PTILE];                   // 16 KB (push1 branch)
    __shared__ int hist[256], st[256], cur[256], gbase[256];
    const int tid = threadIdx.x;

    if (blockIdx.x >= NGEMM) {
        // ---- push1: LDS tile-reorder scatter to coarse buckets (row>>8) ----
        const int t = tid;
        const int i0 = (blockIdx.x - NGEMM) * PTILE;
        const int cnt = min(PTILE, E - i0);
        hist[t] = 0;
        __syncthreads();

        uint u[PTILE / 256];
#pragma unroll
        for (int j = 0; j < PTILE / 256; ++j) {
            const int idx = t + j * 256;
            if (idx < cnt) {
                int r = row[i0 + idx], c = col[i0 + idx];
                u[j] = ((uint)(r >> 8) << 24) | ((uint)c << 8) | (uint)(r & 255);
                atomicAdd(&hist[r >> 8], 1);
            } else u[j] = 0xFFFFFFFFu;
        }
        __syncthreads();

        const int v = hist[t];
        st[t] = v;
        __syncthreads();
        for (int off = 1; off < 256; off <<= 1) {
            int x = (t >= off) ? st[t - off] : 0;
            __syncthreads();
            st[t] += x;
            __syncthreads();
        }
        cur[t] = st[t] - v;                // exclusive start within tile
        if (v) gbase[t] = atomicAdd(&cursorC[t], v);
        __syncthreads();

#pragma unroll
        for (int j = 0; j < PTILE / 256; ++j) {
            if (u[j] != 0xFFFFFFFFu) {
                int k = u[j] >> 24;
                int pos = atomicAdd(&cur[k], 1);
                stage[pos] = u[j];
            }
        }
        __syncthreads();

        for (int p = t; p < cnt; p += 256) {
            uint wv = stage[p];
            int k = wv >> 24;
            int lstart = st[k] - hist[k];
            __builtin_nontemporal_store(wv & 0xFFFFFFu, &cpairs[gbase[k] + (p - lstart)]);
        }
        return;
    }

    // ---- gemm body: full A preload (R12 proven) ----
    const int w = tid >> 6, l = tid & 63;
    const int r0 = blockIdx.x * 64 + w * 16;
    const int rA = min(r0 + (l & 15), n - 1);       // A row (m = lane&15)
    const int kb = (l >> 4) * 8;                    // A k-subgroup

    const float* hp = &h[(size_t)rA * IN_F + kb];
    f32x4 af[16];
#pragma unroll
    for (int ks = 0; ks < 8; ++ks) {                // 16 loads, back-to-back
        af[2 * ks]     = __builtin_nontemporal_load((const f32x4*)(hp + ks * 32));
        af[2 * ks + 1] = __builtin_nontemporal_load((const f32x4*)(hp + ks * 32 + 4));
    }
    uint4 Abf[8];
#pragma unroll
    for (int ks = 0; ks < 8; ++ks) {
        f32x4 a0 = af[2 * ks], a1 = af[2 * ks + 1];
        Abf[ks] = make_uint4(pack2(a0[0], a0[1]), pack2(a0[2], a0[3]),
                             pack2(a1[0], a1[1]), pack2(a1[2], a1[3]));
    }

    f32x4 acc[8];
#pragma unroll
    for (int i = 0; i < 8; ++i) acc[i] = (f32x4)0.f;

#pragma unroll
    for (int ks = 0; ks < 8; ++ks) {
        union { uint4 u; bf16x8 v; } A;
        A.u = Abf[ks];
        const uint4* wp = &Wf[ks * 512 + l];
#pragma unroll
        for (int nt = 0; nt < 8; ++nt) {
            union { uint4 u; bf16x8 v; } B;
            B.u = wp[nt * 64];
            acc[nt] = __builtin_amdgcn_mfma_f32_16x16x32_bf16(A.v, B.v, acc[nt], 0, 0, 0);
        }
    }

    const int c16 = l & 15;
    const int rowm = r0 + 4 * (l >> 4);
    float al[8], ar[8];
#pragma unroll
    for (int H = 0; H < 8; ++H) {
        al[H] = a_l[H * 16 + c16];
        ar[H] = a_r[H * 16 + c16];
    }
#pragma unroll
    for (int reg = 0; reg < 4; ++reg) {
        const int r = rowm + reg;
        float s1v[8], s2v[8];
#pragma unroll
        for (int H = 0; H < 8; ++H) {
            float wv = acc[H][reg];
            s1v[H] = wv * al[H];
            s2v[H] = wv * ar[H];
        }
#pragma unroll
        for (int d = 1; d <= 8; d <<= 1) {
#pragma unroll
            for (int H = 0; H < 8; ++H) {
                s1v[H] += __shfl_xor(s1v[H], d);
                s2v[H] += __shfl_xor(s2v[H], d);
            }
        }
        if (r < n) {
#pragma unroll
            for (int nt = 0; nt < 4; ++nt)
                Whb[(size_t)r * 64 + nt * 16 + c16] = pack2(acc[nt][reg], acc[nt + 4][reg]);
            if (c16 == 0) {
                *(float4*)&Wh1[r * 8]     = make_float4(s1v[0], s1v[1], s1v[2], s1v[3]);
                *(float4*)&Wh1[r * 8 + 4] = make_float4(s1v[4], s1v[5], s1v[6], s1v[7]);
                *(float4*)&Wh2[r * 8]     = make_float4(s2v[0], s2v[1], s2v[2], s2v[3]);
                *(float4*)&Wh2[r * 8 + 4] = make_float4(s2v[4], s2v[5], s2v[6], s2v[7]);
            }
        }
    }
}

// ---------------- push2: coarse slab -> 8 fine slabs (dense both sides) ---------
__global__ __launch_bounds__(256) void push2_kernel(
    const uint* __restrict__ cpairs, const int* __restrict__ cursorC,
    int* __restrict__ cursorF, uint* __restrict__ pairs)
{
    __shared__ int hl[8];
    __shared__ int cur8[8];
    const int c = blockIdx.x;
    const int p0 = c * CSLAB;
    const int ec = cursorC[c] - p0;
    const int t = threadIdx.x;
    if (t < 8) hl[t] = 0;
    __syncthreads();
    for (int p = t; p < ec; p += 256)
        atomicAdd(&hl[(cpairs[p0 + p] >> 5) & 7], 1);
    __syncthreads();
    if (t < 8)
        cur8[t] = hl[t] ? atomicAdd(&cursorF[c * 8 + t], hl[t]) : 0;
    __syncthreads();
    for (int p = t; p < ec; p += 256) {
        uint u = cpairs[p0 + p];
        int pos = atomicAdd(&cur8[(u >> 5) & 7], 1);
        // coarse pair (col<<8)|(row&255) -> fine pair (col<<5)|(row&31)
        __builtin_nontemporal_store(((u >> 8) << 5) | (u & 31), &pairs[pos]);
    }
}

// ---------------- fused CSR-in-LDS + softmax + aggregate (row-pair MLP) ---------
// One WG (4 waves) per 32-row bucket. Phase A: count/scan/scatter cols into LDS.
// Phase B: wave w processes rows in PAIRS (2x independent gathers in flight).
__global__ __launch_bounds__(256) void bucket_gat(
    const uint* __restrict__ pairs, const int* __restrict__ cursorF,
    const uint* __restrict__ Whb, const float* __restrict__ Wh1,
    const float* __restrict__ Wh2, float* __restrict__ out, int n)
{
    __shared__ uint cols_l[SLAB];                   // 8 KB bucket col list
    __shared__ int cnt_l[BS], st0[BS], cur_l[BS];
    const int t = threadIdx.x;
    const int b = blockIdx.x;
    const int p0 = b * SLAB;
    const int ec = cursorF[b] - p0;                 // edges in this bucket

    if (t < BS) cnt_l[t] = 0;
    __syncthreads();
    for (int p = t; p < ec; p += 256)
        atomicAdd(&cnt_l[pairs[p0 + p] & (BS - 1)], 1);
    __syncthreads();
    if (t < BS) {
        int v = cnt_l[t];
        int inc = v;                                // inclusive scan over 32 lanes
#pragma unroll
        for (int off = 1; off < BS; off <<= 1) {
            int x = __shfl_up(inc, off);
            if (t >= off) inc += x;
        }
        st0[t] = inc - v;
        cur_l[t] = inc - v;
    }
    __syncthreads();
    for (int p = t; p < ec; p += 256) {
        uint u = pairs[p0 + p];
        int slot = atomicAdd(&cur_l[u & (BS - 1)], 1);
        cols_l[slot] = u >> BSH;
    }
    __syncthreads();

    const int wv = t >> 6, lane = t & 63;
    const int h8 = lane & 7, es = lane >> 3;
#pragma unroll 1
    for (int ii = 0; ii < 4; ++ii) {
        const int rl0 = wv * 8 + 2 * ii;
        const int rg0 = (b << BSH) + rl0;
        const int rg1 = rg0 + 1;
        const bool v0 = rg0 < n, v1 = rg1 < n;
        const float w1a = v0 ? Wh1[rg0 * HEADS + h8] : 0.f;
        const float w1b = v1 ? Wh1[rg1 * HEADS + h8] : 0.f;
        const int stA = st0[rl0], dA = v0 ? cnt_l[rl0] : 0;
        const int stB = st0[rl0 + 1], dB = v1 ? cnt_l[rl0 + 1] : 0;

        float acc0A = 0.f, acc1A = 0.f, smA = 0.f;
        float acc0B = 0.f, acc1B = 0.f, smB = 0.f;
        const int gmax = max(dA, dB);
        for (int g = 0; g < gmax; g += 8) {
            float exA = 0.f, exB = 0.f;
            if (g < dA) {
                const int kk = g + es;
                const bool valid = kk < dA;
                const uint c = cols_l[stA + (valid ? kk : dA - 1)];
                float e = w1a + Wh2[c * HEADS + h8];
                e = e > 0.f ? e : 0.2f * e;
                e = fminf(e, 60.f);
                exA = valid ? __expf(e) : 0.f;
                smA += exA;
            }
            if (g < dB) {
                const int kk = g + es;
                const bool valid = kk < dB;
                const uint c = cols_l[stB + (valid ? kk : dB - 1)];
                float e = w1b + Wh2[c * HEADS + h8];
                e = e > 0.f ? e : 0.2f * e;
                e = fminf(e, 60.f);
                exB = valid ? __expf(e) : 0.f;
                smB += exB;
            }
            const int mA = dA - g, mB = dB - g;
            if (mA >= 8 && mB >= 8) {               // fast path: both full
#pragma unroll
                for (int k = 0; k < 8; ++k) {
                    float pA = __shfl(exA, k * 8 + h8);
                    float pB = __shfl(exB, k * 8 + h8);
                    uint ckA = cols_l[stA + g + k];
                    uint ckB = cols_l[stB + g + k];
                    uint wbA = Whb[((size_t)ckA << 6) + lane];
                    uint wbB = Whb[((size_t)ckB << 6) + lane];
                    acc0A = fmaf(pA, __uint_as_float(wbA << 16), acc0A);
                    acc1A = fmaf(pA, __uint_as_float(wbA & 0xffff0000u), acc1A);
                    acc0B = fmaf(pB, __uint_as_float(wbB << 16), acc0B);
                    acc1B = fmaf(pB, __uint_as_float(wbB & 0xffff0000u), acc1B);
                }
            } else {
#pragma unroll
                for (int k = 0; k < 8; ++k) {
                    if (k < mA) {
                        float pA = __shfl(exA, k * 8 + h8);
                        uint ck = cols_l[stA + g + k];
                        uint wb = Whb[((size_t)ck << 6) + lane];
                        acc0A = fmaf(pA, __uint_as_float(wb << 16), acc0A);
                        acc1A = fmaf(pA, __uint_as_float(wb & 0xffff0000u), acc1A);
                    }
                    if (k < mB) {
                        float pB = __shfl(exB, k * 8 + h8);
                        uint ck = cols_l[stB + g + k];
                        uint wb = Whb[((size_t)ck << 6) + lane];
                        acc0B = fmaf(pB, __uint_as_float(wb << 16), acc0B);
                        acc1B = fmaf(pB, __uint_as_float(wb & 0xffff0000u), acc1B);
                    }
                }
            }
        }
        smA += __shfl_xor(smA, 8); smA += __shfl_xor(smA, 16); smA += __shfl_xor(smA, 32);
        smB += __shfl_xor(smB, 8); smB += __shfl_xor(smB, 16); smB += __shfl_xor(smB, 32);
        if (v0) {
            const float inv = (dA > 0) ? 1.f / smA : 0.f;
            __builtin_nontemporal_store(fmaxf(acc0A * inv, 0.f), &out[(size_t)rg0 * F + lane]);
            __builtin_nontemporal_store(fmaxf(acc1A * inv, 0.f), &out[(size_t)rg0 * F + 64 + lane]);
        }
        if (v1) {
            const float inv = (dB > 0) ? 1.f / smB : 0.f;
            __builtin_nontemporal_store(fmaxf(acc0B * inv, 0.f), &out[(size_t)rg1 * F + lane]);
            __builtin_nontemporal_store(fmaxf(acc1B * inv, 0.f), &out[(size_t)rg1 * F + 64 + lane]);
        }
    }
}

// ---------------- launch ----------------
extern "C" void kernel_launch(void* const* d_in, const int* in_sizes, int n_in,
                              void* d_out, int out_size, void* d_ws, size_t ws_size,
                              hipStream_t stream)
{
    const int* row = (const int*)d_in[0];
    const int* col = (const int*)d_in[1];
    const float* h   = (const float*)d_in[2];
    const float* W   = (const float*)d_in[3];
    const float* a_l = (const float*)d_in[4];
    const float* a_r = (const float*)d_in[5];
    const int E = in_sizes[0];
    const int n = in_sizes[2] / IN_F;
    float* out = (float*)d_out;
    const int NBF = (n + BS - 1) >> BSH;                // fine buckets (1563)
    const int NC  = (n + 255) >> 8;                     // coarse buckets (196)
    const int NGEMM = (n + 63) / 64;
    const int NPUSH = (E + PTILE - 1) / PTILE;

    char* p = (char*)d_ws;
    auto alloc = [&](size_t bytes) -> char* {
        char* q = p;
        p += (bytes + 255) & ~(size_t)255;
        return q;
    };
    uint*  Whb     = (uint*)alloc((size_t)n * 64 * 4);  // paired bf16 cols (l, l+64)
    float* Wh1     = (float*)alloc((size_t)n * HEADS * 4);
    float* Wh2     = (float*)alloc((size_t)n * HEADS * 4);
    uint4* Wf      = (uint4*)alloc(8 * 8 * 64 * 16);    // prepacked W fragments
    int*   cursorC = (int*)alloc((size_t)NC * 4);
    int*   cursorF = (int*)alloc((size_t)NBF * 4);
    uint*  cpairs  = (uint*)alloc((size_t)NC * CSLAB * 4);
    uint*  pairs   = (uint*)alloc((size_t)NBF * SLAB * 4);

    prepack<<<16, 256, 0, stream>>>(W, Wf, cursorC, cursorF, NC, NBF);
    gemm_push<<<NGEMM + NPUSH, 256, 0, stream>>>(h, Wf, a_l, a_r, Whb, Wh1, Wh2,
                                                 n, NGEMM, row, col, cursorC, cpairs, E);
    push2_kernel<<<NC, 256, 0, stream>>>(cpairs, cursorC, cursorF, pairs);
    bucket_gat<<<NBF, 256, 0, stream>>>(pairs, cursorF, Whb, Wh1, Wh2, out, n);
}

// Round 14
// 138.529 us; speedup vs baseline: 1.2669x; 1.2669x over previous
//
#include <hip/hip_runtime.h>
#include <cfloat>
#include <math.h>

// GATConv fused pipeline for MI355X.
// inputs: row[E] i32, col[E] i32, h[N,256] f32, W[256,128] f32, a_l[8,16] f32, a_r[8,16] f32
// output: relu(h_prime) [N,16,8] f32.
//
// R14 = proven parts only (R13 post-mortem: fusion good, row-pair gat bad):
//  prepack    : W -> MFMA B-fragments + cursor inits.
//  gemm_push  : fused dispatch. Blocks [0,NGEMM): MFMA bf16 gemm, full A preload
//               (R12). Blocks [NGEMM,+NPUSH): push1 LDS tile-reorder radix
//               scatter to 196 coarse buckets (dense burst writes).
//  push2      : coarse slab -> 8 fine slabs (dense both sides).
//  bucket_gat : R12-verbatim single-row loop (72.5us; pairing/tiling variants
//               regressed twice -- compiler already pipelines this shape).

constexpr int IN_F  = 256;
constexpr int F     = 128;   // OUT*HEADS
constexpr int HEADS = 8;
constexpr int BS    = 32;    // rows per fine bucket
constexpr int BSH   = 5;
constexpr int SLAB  = 2048;  // fine slab capacity (avg 1024, ~32 sigma)
constexpr int CSLAB = 9216;  // coarse slab capacity (avg 8192, ~11 sigma)
constexpr int PTILE = 4096;  // push1 tile size

typedef __attribute__((ext_vector_type(8))) short bf16x8;  // 8 bf16 in 4 VGPRs
typedef __attribute__((ext_vector_type(4))) float f32x4;

__device__ inline uint f2bf(float x) {              // f32 -> bf16 RNE (upper 16 bits)
    uint u = __float_as_uint(x);
    return (u + 0x7fffu + ((u >> 16) & 1u)) >> 16;
}
__device__ inline uint pack2(float a, float b) { return f2bf(a) | (f2bf(b) << 16); }

// ---------------- W prepack + cursor inits --------------------------------------
__global__ __launch_bounds__(256) void prepack(const float* __restrict__ W,
                                               uint4* __restrict__ Wf,
                                               int* __restrict__ cursorC,
                                               int* __restrict__ cursorF,
                                               int NC, int NBF)
{
    if (blockIdx.x == 0) {
        for (int i = threadIdx.x; i < NC; i += 256) cursorC[i] = i * CSLAB;
        for (int i = threadIdx.x; i < NBF; i += 256) cursorF[i] = i * SLAB;
    }
    int t = blockIdx.x * 256 + threadIdx.x;
    if (t >= 8 * 8 * 64) return;
    int ks = t >> 9, nt = (t >> 6) & 7, l = t & 63;
    int col = nt * 16 + (l & 15);
    int k0 = ks * 32 + (l >> 4) * 8;
    float v[8];
#pragma unroll
    for (int i = 0; i < 8; ++i) v[i] = W[(size_t)(k0 + i) * F + col];
    Wf[t] = make_uint4(pack2(v[0], v[1]), pack2(v[2], v[3]),
                       pack2(v[4], v[5]), pack2(v[6], v[7]));
}

// ---------------- fused: MFMA GEMM (blocks < NGEMM) + push1 (rest) --------------
__global__ __launch_bounds__(256) void gemm_push(
    const float* __restrict__ h, const uint4* __restrict__ Wf,
    const float* __restrict__ a_l, const float* __restrict__ a_r,
    uint* __restrict__ Whb, float* __restrict__ Wh1, float* __restrict__ Wh2,
    int n, int NGEMM,
    const int* __restrict__ row, const int* __restrict__ col,
    int* __restrict__ cursorC, uint* __restrict__ cpairs, int E)
{
    __shared__ uint stage[PTILE];                   // 16 KB (push1 branch)
    __shared__ int hist[256], st[256], cur[256], gbase[256];
    const int tid = threadIdx.x;

    if (blockIdx.x >= NGEMM) {
        // ---- push1: LDS tile-reorder scatter to coarse buckets (row>>8) ----
        const int t = tid;
        const int i0 = (blockIdx.x - NGEMM) * PTILE;
        const int cnt = min(PTILE, E - i0);
        hist[t] = 0;
        __syncthreads();

        uint u[PTILE / 256];
#pragma unroll
        for (int j = 0; j < PTILE / 256; ++j) {
            const int idx = t + j * 256;
            if (idx < cnt) {
                int r = row[i0 + idx], c = col[i0 + idx];
                u[j] = ((uint)(r >> 8) << 24) | ((uint)c << 8) | (uint)(r & 255);
                atomicAdd(&hist[r >> 8], 1);
            } else u[j] = 0xFFFFFFFFu;
        }
        __syncthreads();

        const int v = hist[t];
        st[t] = v;
        __syncthreads();
        for (int off = 1; off < 256; off <<= 1) {
            int x = (t >= off) ? st[t - off] : 0;
            __syncthreads();
            st[t] += x;
            __syncthreads();
        }
        cur[t] = st[t] - v;                // exclusive start within tile
        if (v) gbase[t] = atomicAdd(&cursorC[t], v);
        __syncthreads();

#pragma unroll
        for (int j = 0; j < PTILE / 256; ++j) {
            if (u[j] != 0xFFFFFFFFu) {
                int k = u[j] >> 24;
                int pos = atomicAdd(&cur[k], 1);
                stage[pos] = u[j];
            }
        }
        __syncthreads();

        for (int p = t; p < cnt; p += 256) {
            uint wv = stage[p];
            int k = wv >> 24;
            int lstart = st[k] - hist[k];
            __builtin_nontemporal_store(wv & 0xFFFFFFu, &cpairs[gbase[k] + (p - lstart)]);
        }
        return;
    }

    // ---- gemm body: full A preload (R12 proven) ----
    const int w = tid >> 6, l = tid & 63;
    const int r0 = blockIdx.x * 64 + w * 16;
    const int rA = min(r0 + (l & 15), n - 1);       // A row (m = lane&15)
    const int kb = (l >> 4) * 8;                    // A k-subgroup

    const float* hp = &h[(size_t)rA * IN_F + kb];
    f32x4 af[16];
#pragma unroll
    for (int ks = 0; ks < 8; ++ks) {                // 16 loads, back-to-back
        af[2 * ks]     = __builtin_nontemporal_load((const f32x4*)(hp + ks * 32));
        af[2 * ks + 1] = __builtin_nontemporal_load((const f32x4*)(hp + ks * 32 + 4));
    }
    uint4 Abf[8];
#pragma unroll
    for (int ks = 0; ks < 8; ++ks) {
        f32x4 a0 = af[2 * ks], a1 = af[2 * ks + 1];
        Abf[ks] = make_uint4(pack2(a0[0], a0[1]), pack2(a0[2], a0[3]),
                             pack2(a1[0], a1[1]), pack2(a1[2], a1[3]));
    }

    f32x4 acc[8];
#pragma unroll
    for (int i = 0; i < 8; ++i) acc[i] = (f32x4)0.f;

#pragma unroll
    for (int ks = 0; ks < 8; ++ks) {
        union { uint4 u; bf16x8 v; } A;
        A.u = Abf[ks];
        const uint4* wp = &Wf[ks * 512 + l];
#pragma unroll
        for (int nt = 0; nt < 8; ++nt) {
            union { uint4 u; bf16x8 v; } B;
            B.u = wp[nt * 64];
            acc[nt] = __builtin_amdgcn_mfma_f32_16x16x32_bf16(A.v, B.v, acc[nt], 0, 0, 0);
        }
    }

    const int c16 = l & 15;
    const int rowm = r0 + 4 * (l >> 4);
    float al[8], ar[8];
#pragma unroll
    for (int H = 0; H < 8; ++H) {
        al[H] = a_l[H * 16 + c16];
        ar[H] = a_r[H * 16 + c16];
    }
#pragma unroll
    for (int reg = 0; reg < 4; ++reg) {
        const int r = rowm + reg;
        float s1v[8], s2v[8];
#pragma unroll
        for (int H = 0; H < 8; ++H) {
            float wv = acc[H][reg];
            s1v[H] = wv * al[H];
            s2v[H] = wv * ar[H];
        }
#pragma unroll
        for (int d = 1; d <= 8; d <<= 1) {
#pragma unroll
            for (int H = 0; H < 8; ++H) {
                s1v[H] += __shfl_xor(s1v[H], d);
                s2v[H] += __shfl_xor(s2v[H], d);
            }
        }
        if (r < n) {
#pragma unroll
            for (int nt = 0; nt < 4; ++nt)
                Whb[(size_t)r * 64 + nt * 16 + c16] = pack2(acc[nt][reg], acc[nt + 4][reg]);
            if (c16 == 0) {
                *(float4*)&Wh1[r * 8]     = make_float4(s1v[0], s1v[1], s1v[2], s1v[3]);
                *(float4*)&Wh1[r * 8 + 4] = make_float4(s1v[4], s1v[5], s1v[6], s1v[7]);
                *(float4*)&Wh2[r * 8]     = make_float4(s2v[0], s2v[1], s2v[2], s2v[3]);
                *(float4*)&Wh2[r * 8 + 4] = make_float4(s2v[4], s2v[5], s2v[6], s2v[7]);
            }
        }
    }
}

// ---------------- push2: coarse slab -> 8 fine slabs (dense both sides) ---------
__global__ __launch_bounds__(256) void push2_kernel(
    const uint* __restrict__ cpairs, const int* __restrict__ cursorC,
    int* __restrict__ cursorF, uint* __restrict__ pairs)
{
    __shared__ int hl[8];
    __shared__ int cur8[8];
    const int c = blockIdx.x;
    const int p0 = c * CSLAB;
    const int ec = cursorC[c] - p0;
    const int t = threadIdx.x;
    if (t < 8) hl[t] = 0;
    __syncthreads();
    for (int p = t; p < ec; p += 256)
        atomicAdd(&hl[(cpairs[p0 + p] >> 5) & 7], 1);
    __syncthreads();
    if (t < 8)
        cur8[t] = hl[t] ? atomicAdd(&cursorF[c * 8 + t], hl[t]) : 0;
    __syncthreads();
    for (int p = t; p < ec; p += 256) {
        uint u = cpairs[p0 + p];
        int pos = atomicAdd(&cur8[(u >> 5) & 7], 1);
        // coarse pair (col<<8)|(row&255) -> fine pair (col<<5)|(row&31)
        __builtin_nontemporal_store(((u >> 8) << 5) | (u & 31), &pairs[pos]);
    }
}

// ---------------- fused CSR-in-LDS + softmax + aggregate (R12 verbatim) ---------
// One WG (4 waves) per 32-row bucket. Phase A: count/scan/scatter cols into LDS.
// Phase B: wave w processes rows w*8..w*8+7 with the 8-edge-slot gather loop.
__global__ __launch_bounds__(256) void bucket_gat(
    const uint* __restrict__ pairs, const int* __restrict__ cursorF,
    const uint* __restrict__ Whb, const float* __restrict__ Wh1,
    const float* __restrict__ Wh2, float* __restrict__ out, int n)
{
    __shared__ uint cols_l[SLAB];                   // 8 KB bucket col list
    __shared__ int cnt_l[BS], st0[BS], cur_l[BS];
    const int t = threadIdx.x;
    const int b = blockIdx.x;
    const int p0 = b * SLAB;
    const int ec = cursorF[b] - p0;                 // edges in this bucket

    if (t < BS) cnt_l[t] = 0;
    __syncthreads();
    for (int p = t; p < ec; p += 256)
        atomicAdd(&cnt_l[pairs[p0 + p] & (BS - 1)], 1);
    __syncthreads();
    if (t < BS) {
        int v = cnt_l[t];
        int inc = v;                                // inclusive scan over 32 lanes
#pragma unroll
        for (int off = 1; off < BS; off <<= 1) {
            int x = __shfl_up(inc, off);
            if (t >= off) inc += x;
        }
        st0[t] = inc - v;
        cur_l[t] = inc - v;
    }
    __syncthreads();
    for (int p = t; p < ec; p += 256) {
        uint u = pairs[p0 + p];
        int slot = atomicAdd(&cur_l[u & (BS - 1)], 1);
        cols_l[slot] = u >> BSH;
    }
    __syncthreads();

    const int wv = t >> 6, lane = t & 63;
    const int h8 = lane & 7, es = lane >> 3;
#pragma unroll 1
    for (int i = 0; i < 8; ++i) {
        const int rl = wv * 8 + i;
        const int r = (b << BSH) + rl;
        if (r >= n) continue;
        const float w1 = Wh1[r * HEADS + h8];
        const int st = st0[rl];
        const int deg = cnt_l[rl];

        float acc0 = 0.f, acc1 = 0.f, sm = 0.f;
        for (int g = 0; g < deg; g += 8) {
            const int kk = g + es;
            const bool valid = kk < deg;
            const uint c = cols_l[st + (valid ? kk : deg - 1)];
            float e = w1 + Wh2[c * HEADS + h8];
            e = e > 0.f ? e : 0.2f * e;
            e = fminf(e, 60.f);                     // overflow guard
            const float ex = valid ? __expf(e) : 0.f;
            sm += ex;
            const int m8 = deg - g;
            if (m8 >= 8) {
#pragma unroll
                for (int k = 0; k < 8; ++k) {
                    float pA = __shfl(ex, k * 8 + h8);
                    uint ck = cols_l[st + g + k];
                    uint wb = Whb[((size_t)ck << 6) + lane];
                    acc0 = fmaf(pA, __uint_as_float(wb << 16), acc0);
                    acc1 = fmaf(pA, __uint_as_float(wb & 0xffff0000u), acc1);
                }
            } else {
                for (int k = 0; k < m8; ++k) {
                    float pA = __shfl(ex, k * 8 + h8);
                    uint ck = cols_l[st + g + k];
                    uint wb = Whb[((size_t)ck << 6) + lane];
                    acc0 = fmaf(pA, __uint_as_float(wb << 16), acc0);
                    acc1 = fmaf(pA, __uint_as_float(wb & 0xffff0000u), acc1);
                }
            }
        }
        sm += __shfl_xor(sm, 8);
        sm += __shfl_xor(sm, 16);
        sm += __shfl_xor(sm, 32);
        const float inv = (deg > 0) ? 1.f / sm : 0.f;
        __builtin_nontemporal_store(fmaxf(acc0 * inv, 0.f), &out[(size_t)r * F + lane]);
        __builtin_nontemporal_store(fmaxf(acc1 * inv, 0.f), &out[(size_t)r * F + 64 + lane]);
    }
}

// ---------------- launch ----------------
extern "C" void kernel_launch(void* const* d_in, const int* in_sizes, int n_in,
                              void* d_out, int out_size, void* d_ws, size_t ws_size,
                              hipStream_t stream)
{
    const int* row = (const int*)d_in[0];
    const int* col = (const int*)d_in[1];
    const float* h   = (const float*)d_in[2];
    const float* W   = (const float*)d_in[3];
    const float* a_l = (const float*)d_in[4];
    const float* a_r = (const float*)d_in[5];
    const int E = in_sizes[0];
    const int n = in_sizes[2] / IN_F;
    float* out = (float*)d_out;
    const int NBF = (n + BS - 1) >> BSH;                // fine buckets (1563)
    const int NC  = (n + 255) >> 8;                     // coarse buckets (196)
    const int NGEMM = (n + 63) / 64;
    const int NPUSH = (E + PTILE - 1) / PTILE;

    char* p = (char*)d_ws;
    auto alloc = [&](size_t bytes) -> char* {
        char* q = p;
        p += (bytes + 255) & ~(size_t)255;
        return q;
    };
    uint*  Whb     = (uint*)alloc((size_t)n * 64 * 4);  // paired bf16 cols (l, l+64)
    float* Wh1     = (float*)alloc((size_t)n * HEADS * 4);
    float* Wh2     = (float*)alloc((size_t)n * HEADS * 4);
    uint4* Wf      = (uint4*)alloc(8 * 8 * 64 * 16);    // prepacked W fragments
    int*   cursorC = (int*)alloc((size_t)NC * 4);
    int*   cursorF = (int*)alloc((size_t)NBF * 4);
    uint*  cpairs  = (uint*)alloc((size_t)NC * CSLAB * 4);
    uint*  pairs   = (uint*)alloc((size_t)NBF * SLAB * 4);

    prepack<<<16, 256, 0, stream>>>(W, Wf, cursorC, cursorF, NC, NBF);
    gemm_push<<<NGEMM + NPUSH, 256, 0, stream>>>(h, Wf, a_l, a_r, Whb, Wh1, Wh2,
                                                 n, NGEMM, row, col, cursorC, cpairs, E);
    push2_kernel<<<NC, 256, 0, stream>>>(cpairs, cursorC, cursorF, pairs);
    bucket_gat<<<NBF, 256, 0, stream>>>(pairs, cursorF, Whb, Wh1, Wh2, out, n);
}

// Round 15
// 138.292 us; speedup vs baseline: 1.2691x; 1.0017x over previous
//
#include <hip/hip_runtime.h>
#include <cfloat>
#include <math.h>

// GATConv fused pipeline for MI355X.
// inputs: row[E] i32, col[E] i32, h[N,256] f32, W[256,128] f32, a_l[8,16] f32, a_r[8,16] f32
// output: relu(h_prime) [N,16,8] f32.
//
// R15 = R14 + bucket_gat software pipeline:
//  - steady-state loop over FULL groups is branch-free (remainder peeled once);
//  - next group's Wh2-gather + exp computed BEFORE current group's k-loop, so the
//    ~300-600cy Wh2/exp chain (previously serialized between groups) hides under
//    the k-loop's Whb gather stalls. Inner k-loop kept verbatim (R13 lesson:
//    don't touch the proven 8-wide shape).
//  Everything else identical to R14.

constexpr int IN_F  = 256;
constexpr int F     = 128;   // OUT*HEADS
constexpr int HEADS = 8;
constexpr int BS    = 32;    // rows per fine bucket
constexpr int BSH   = 5;
constexpr int SLAB  = 2048;  // fine slab capacity (avg 1024, ~32 sigma)
constexpr int CSLAB = 9216;  // coarse slab capacity (avg 8192, ~11 sigma)
constexpr int PTILE = 4096;  // push1 tile size

typedef __attribute__((ext_vector_type(8))) short bf16x8;  // 8 bf16 in 4 VGPRs
typedef __attribute__((ext_vector_type(4))) float f32x4;

__device__ inline uint f2bf(float x) {              // f32 -> bf16 RNE (upper 16 bits)
    uint u = __float_as_uint(x);
    return (u + 0x7fffu + ((u >> 16) & 1u)) >> 16;
}
__device__ inline uint pack2(float a, float b) { return f2bf(a) | (f2bf(b) << 16); }

// ---------------- W prepack + cursor inits --------------------------------------
__global__ __launch_bounds__(256) void prepack(const float* __restrict__ W,
                                               uint4* __restrict__ Wf,
                                               int* __restrict__ cursorC,
                                               int* __restrict__ cursorF,
                                               int NC, int NBF)
{
    if (blockIdx.x == 0) {
        for (int i = threadIdx.x; i < NC; i += 256) cursorC[i] = i * CSLAB;
        for (int i = threadIdx.x; i < NBF; i += 256) cursorF[i] = i * SLAB;
    }
    int t = blockIdx.x * 256 + threadIdx.x;
    if (t >= 8 * 8 * 64) return;
    int ks = t >> 9, nt = (t >> 6) & 7, l = t & 63;
    int col = nt * 16 + (l & 15);
    int k0 = ks * 32 + (l >> 4) * 8;
    float v[8];
#pragma unroll
    for (int i = 0; i < 8; ++i) v[i] = W[(size_t)(k0 + i) * F + col];
    Wf[t] = make_uint4(pack2(v[0], v[1]), pack2(v[2], v[3]),
                       pack2(v[4], v[5]), pack2(v[6], v[7]));
}

// ---------------- fused: MFMA GEMM (blocks < NGEMM) + push1 (rest) --------------
__global__ __launch_bounds__(256) void gemm_push(
    const float* __restrict__ h, const uint4* __restrict__ Wf,
    const float* __restrict__ a_l, const float* __restrict__ a_r,
    uint* __restrict__ Whb, float* __restrict__ Wh1, float* __restrict__ Wh2,
    int n, int NGEMM,
    const int* __restrict__ row, const int* __restrict__ col,
    int* __restrict__ cursorC, uint* __restrict__ cpairs, int E)
{
    __shared__ uint stage[PTILE];                   // 16 KB (push1 branch)
    __shared__ int hist[256], st[256], cur[256], gbase[256];
    const int tid = threadIdx.x;

    if (blockIdx.x >= NGEMM) {
        // ---- push1: LDS tile-reorder scatter to coarse buckets (row>>8) ----
        const int t = tid;
        const int i0 = (blockIdx.x - NGEMM) * PTILE;
        const int cnt = min(PTILE, E - i0);
        hist[t] = 0;
        __syncthreads();

        uint u[PTILE / 256];
#pragma unroll
        for (int j = 0; j < PTILE / 256; ++j) {
            const int idx = t + j * 256;
            if (idx < cnt) {
                int r = row[i0 + idx], c = col[i0 + idx];
                u[j] = ((uint)(r >> 8) << 24) | ((uint)c << 8) | (uint)(r & 255);
                atomicAdd(&hist[r >> 8], 1);
            } else u[j] = 0xFFFFFFFFu;
        }
        __syncthreads();

        const int v = hist[t];
        st[t] = v;
        __syncthreads();
        for (int off = 1; off < 256; off <<= 1) {
            int x = (t >= off) ? st[t - off] : 0;
            __syncthreads();
            st[t] += x;
            __syncthreads();
        }
        cur[t] = st[t] - v;                // exclusive start within tile
        if (v) gbase[t] = atomicAdd(&cursorC[t], v);
        __syncthreads();

#pragma unroll
        for (int j = 0; j < PTILE / 256; ++j) {
            if (u[j] != 0xFFFFFFFFu) {
                int k = u[j] >> 24;
                int pos = atomicAdd(&cur[k], 1);
                stage[pos] = u[j];
            }
        }
        __syncthreads();

        for (int p = t; p < cnt; p += 256) {
            uint wv = stage[p];
            int k = wv >> 24;
            int lstart = st[k] - hist[k];
            __builtin_nontemporal_store(wv & 0xFFFFFFu, &cpairs[gbase[k] + (p - lstart)]);
        }
        return;
    }

    // ---- gemm body: full A preload (R12 proven) ----
    const int w = tid >> 6, l = tid & 63;
    const int r0 = blockIdx.x * 64 + w * 16;
    const int rA = min(r0 + (l & 15), n - 1);       // A row (m = lane&15)
    const int kb = (l >> 4) * 8;                    // A k-subgroup

    const float* hp = &h[(size_t)rA * IN_F + kb];
    f32x4 af[16];
#pragma unroll
    for (int ks = 0; ks < 8; ++ks) {                // 16 loads, back-to-back
        af[2 * ks]     = __builtin_nontemporal_load((const f32x4*)(hp + ks * 32));
        af[2 * ks + 1] = __builtin_nontemporal_load((const f32x4*)(hp + ks * 32 + 4));
    }
    uint4 Abf[8];
#pragma unroll
    for (int ks = 0; ks < 8; ++ks) {
        f32x4 a0 = af[2 * ks], a1 = af[2 * ks + 1];
        Abf[ks] = make_uint4(pack2(a0[0], a0[1]), pack2(a0[2], a0[3]),
                             pack2(a1[0], a1[1]), pack2(a1[2], a1[3]));
    }

    f32x4 acc[8];
#pragma unroll
    for (int i = 0; i < 8; ++i) acc[i] = (f32x4)0.f;

#pragma unroll
    for (int ks = 0; ks < 8; ++ks) {
        union { uint4 u; bf16x8 v; } A;
        A.u = Abf[ks];
        const uint4* wp = &Wf[ks * 512 + l];
#pragma unroll
        for (int nt = 0; nt < 8; ++nt) {
            union { uint4 u; bf16x8 v; } B;
            B.u = wp[nt * 64];
            acc[nt] = __builtin_amdgcn_mfma_f32_16x16x32_bf16(A.v, B.v, acc[nt], 0, 0, 0);
        }
    }

    const int c16 = l & 15;
    const int rowm = r0 + 4 * (l >> 4);
    float al[8], ar[8];
#pragma unroll
    for (int H = 0; H < 8; ++H) {
        al[H] = a_l[H * 16 + c16];
        ar[H] = a_r[H * 16 + c16];
    }
#pragma unroll
    for (int reg = 0; reg < 4; ++reg) {
        const int r = rowm + reg;
        float s1v[8], s2v[8];
#pragma unroll
        for (int H = 0; H < 8; ++H) {
            float wv = acc[H][reg];
            s1v[H] = wv * al[H];
            s2v[H] = wv * ar[H];
        }
#pragma unroll
        for (int d = 1; d <= 8; d <<= 1) {
#pragma unroll
            for (int H = 0; H < 8; ++H) {
                s1v[H] += __shfl_xor(s1v[H], d);
                s2v[H] += __shfl_xor(s2v[H], d);
            }
        }
        if (r < n) {
#pragma unroll
            for (int nt = 0; nt < 4; ++nt)
                Whb[(size_t)r * 64 + nt * 16 + c16] = pack2(acc[nt][reg], acc[nt + 4][reg]);
            if (c16 == 0) {
                *(float4*)&Wh1[r * 8]     = make_float4(s1v[0], s1v[1], s1v[2], s1v[3]);
                *(float4*)&Wh1[r * 8 + 4] = make_float4(s1v[4], s1v[5], s1v[6], s1v[7]);
                *(float4*)&Wh2[r * 8]     = make_float4(s2v[0], s2v[1], s2v[2], s2v[3]);
                *(float4*)&Wh2[r * 8 + 4] = make_float4(s2v[4], s2v[5], s2v[6], s2v[7]);
            }
        }
    }
}

// ---------------- push2: coarse slab -> 8 fine slabs (dense both sides) ---------
__global__ __launch_bounds__(256) void push2_kernel(
    const uint* __restrict__ cpairs, const int* __restrict__ cursorC,
    int* __restrict__ cursorF, uint* __restrict__ pairs)
{
    __shared__ int hl[8];
    __shared__ int cur8[8];
    const int c = blockIdx.x;
    const int p0 = c * CSLAB;
    const int ec = cursorC[c] - p0;
    const int t = threadIdx.x;
    if (t < 8) hl[t] = 0;
    __syncthreads();
    for (int p = t; p < ec; p += 256)
        atomicAdd(&hl[(cpairs[p0 + p] >> 5) & 7], 1);
    __syncthreads();
    if (t < 8)
        cur8[t] = hl[t] ? atomicAdd(&cursorF[c * 8 + t], hl[t]) : 0;
    __syncthreads();
    for (int p = t; p < ec; p += 256) {
        uint u = cpairs[p0 + p];
        int pos = atomicAdd(&cur8[(u >> 5) & 7], 1);
        // coarse pair (col<<8)|(row&255) -> fine pair (col<<5)|(row&31)
        __builtin_nontemporal_store(((u >> 8) << 5) | (u & 31), &pairs[pos]);
    }
}

// ---------------- fused CSR-in-LDS + softmax + aggregate (pipelined ex) ---------
// One WG (4 waves) per 32-row bucket. Phase A: count/scan/scatter cols into LDS.
// Phase B: single-row loop (proven shape); next group's Wh2-gather+exp computed
// before the current group's k-loop (hides the serialized Wh2/exp chain).
__global__ __launch_bounds__(256) void bucket_gat(
    const uint* __restrict__ pairs, const int* __restrict__ cursorF,
    const uint* __restrict__ Whb, const float* __restrict__ Wh1,
    const float* __restrict__ Wh2, float* __restrict__ out, int n)
{
    __shared__ uint cols_l[SLAB];                   // 8 KB bucket col list
    __shared__ int cnt_l[BS], st0[BS], cur_l[BS];
    const int t = threadIdx.x;
    const int b = blockIdx.x;
    const int p0 = b * SLAB;
    const int ec = cursorF[b] - p0;                 // edges in this bucket

    if (t < BS) cnt_l[t] = 0;
    __syncthreads();
    for (int p = t; p < ec; p += 256)
        atomicAdd(&cnt_l[pairs[p0 + p] & (BS - 1)], 1);
    __syncthreads();
    if (t < BS) {
        int v = cnt_l[t];
        int inc = v;                                // inclusive scan over 32 lanes
#pragma unroll
        for (int off = 1; off < BS; off <<= 1) {
            int x = __shfl_up(inc, off);
            if (t >= off) inc += x;
        }
        st0[t] = inc - v;
        cur_l[t] = inc - v;
    }
    __syncthreads();
    for (int p = t; p < ec; p += 256) {
        uint u = pairs[p0 + p];
        int slot = atomicAdd(&cur_l[u & (BS - 1)], 1);
        cols_l[slot] = u >> BSH;
    }
    __syncthreads();

    const int wv = t >> 6, lane = t & 63;
    const int h8 = lane & 7, es = lane >> 3;
#pragma unroll 1
    for (int i = 0; i < 8; ++i) {
        const int rl = wv * 8 + i;
        const int r = (b << BSH) + rl;
        if (r >= n) continue;
        const float w1 = Wh1[r * HEADS + h8];
        const int st = st0[rl];
        const int deg = cnt_l[rl];
        if (deg == 0) {
            __builtin_nontemporal_store(0.f, &out[(size_t)r * F + lane]);
            __builtin_nontemporal_store(0.f, &out[(size_t)r * F + 64 + lane]);
            continue;
        }

        // ex for group g (8 edges, lane-slot es, head h8)
        auto calc_ex = [&](int g) -> float {
            const int kk = g + es;
            const bool valid = kk < deg;
            const uint c = cols_l[st + (valid ? kk : deg - 1)];
            float e = w1 + Wh2[c * HEADS + h8];
            e = e > 0.f ? e : 0.2f * e;
            e = fminf(e, 60.f);                     // overflow guard
            return valid ? __expf(e) : 0.f;
        };

        float acc0 = 0.f, acc1 = 0.f, sm = 0.f;
        const int nfull8 = deg & ~7;                // full-group edge count
        float ex = calc_ex(0);                      // pipeline prologue

#pragma unroll 1
        for (int g = 0; g < nfull8; g += 8) {
            // issue next group's Wh2 gather + exp BEFORE this group's k-loop
            const float exn = (g + 8 < deg) ? calc_ex(g + 8) : 0.f;
            sm += ex;
#pragma unroll
            for (int k = 0; k < 8; ++k) {           // proven k-loop, verbatim
                float pA = __shfl(ex, k * 8 + h8);
                uint ck = cols_l[st + g + k];
                uint wb = Whb[((size_t)ck << 6) + lane];
                acc0 = fmaf(pA, __uint_as_float(wb << 16), acc0);
                acc1 = fmaf(pA, __uint_as_float(wb & 0xffff0000u), acc1);
            }
            ex = exn;
        }
        // remainder group (0..7 edges), handled once
        if (nfull8 < deg) {
            sm += ex;
            const int m8 = deg - nfull8;
            for (int k = 0; k < m8; ++k) {
                float pA = __shfl(ex, k * 8 + h8);
                uint ck = cols_l[st + nfull8 + k];
                uint wb = Whb[((size_t)ck << 6) + lane];
                acc0 = fmaf(pA, __uint_as_float(wb << 16), acc0);
                acc1 = fmaf(pA, __uint_as_float(wb & 0xffff0000u), acc1);
            }
        }

        sm += __shfl_xor(sm, 8);
        sm += __shfl_xor(sm, 16);
        sm += __shfl_xor(sm, 32);
        const float inv = 1.f / sm;
        __builtin_nontemporal_store(fmaxf(acc0 * inv, 0.f), &out[(size_t)r * F + lane]);
        __builtin_nontemporal_store(fmaxf(acc1 * inv, 0.f), &out[(size_t)r * F + 64 + lane]);
    }
}

// ---------------- launch ----------------
extern "C" void kernel_launch(void* const* d_in, const int* in_sizes, int n_in,
                              void* d_out, int out_size, void* d_ws, size_t ws_size,
                              hipStream_t stream)
{
    const int* row = (const int*)d_in[0];
    const int* col = (const int*)d_in[1];
    const float* h   = (const float*)d_in[2];
    const float* W   = (const float*)d_in[3];
    const float* a_l = (const float*)d_in[4];
    const float* a_r = (const float*)d_in[5];
    const int E = in_sizes[0];
    const int n = in_sizes[2] / IN_F;
    float* out = (float*)d_out;
    const int NBF = (n + BS - 1) >> BSH;                // fine buckets (1563)
    const int NC  = (n + 255) >> 8;                     // coarse buckets (196)
    const int NGEMM = (n + 63) / 64;
    const int NPUSH = (E + PTILE - 1) / PTILE;

    char* p = (char*)d_ws;
    auto alloc = [&](size_t bytes) -> char* {
        char* q = p;
        p += (bytes + 255) & ~(size_t)255;
        return q;
    };
    uint*  Whb     = (uint*)alloc((size_t)n * 64 * 4);  // paired bf16 cols (l, l+64)
    float* Wh1     = (float*)alloc((size_t)n * HEADS * 4);
    float* Wh2     = (float*)alloc((size_t)n * HEADS * 4);
    uint4* Wf      = (uint4*)alloc(8 * 8 * 64 * 16);    // prepacked W fragments
    int*   cursorC = (int*)alloc((size_t)NC * 4);
    int*   cursorF = (int*)alloc((size_t)NBF * 4);
    uint*  cpairs  = (uint*)alloc((size_t)NC * CSLAB * 4);
    uint*  pairs   = (uint*)alloc((size_t)NBF * SLAB * 4);

    prepack<<<16, 256, 0, stream>>>(W, Wf, cursorC, cursorF, NC, NBF);
    gemm_push<<<NGEMM + NPUSH, 256, 0, stream>>>(h, Wf, a_l, a_r, Whb, Wh1, Wh2,
                                                 n, NGEMM, row, col, cursorC, cpairs, E);
    push2_kernel<<<NC, 256, 0, stream>>>(cpairs, cursorC, cursorF, pairs);
    bucket_gat<<<NBF, 256, 0, stream>>>(pairs, cursorF, Whb, Wh1, Wh2, out, n);
}

// Round 16
// 133.194 us; speedup vs baseline: 1.3177x; 1.0383x over previous
//
#include <hip/hip_runtime.h>
#include <cfloat>
#include <math.h>

// GATConv fused pipeline for MI355X.
// inputs: row[E] i32, col[E] i32, h[N,256] f32, W[256,128] f32, a_l[8,16] f32, a_r[8,16] f32
// output: relu(h_prime) [N,16,8] f32.
//
// R16: 3-dispatch schedule (R15 post-mortem: gat pinned at L2/L3 gather service
//      ceiling ~72us across 4 structural variants; remaining fat = mid-pipeline
//      serialization, not any kernel's roofline):
//   memset ccnt/fcnt (count cursors, zero-based -- removes same-dispatch init race)
//   A: push1 (LDS tile-reorder scatter -> coarse buckets) || prepack (W fragments)
//   B: push2 (coarse -> 8 fine slabs)                     || gemm (MFMA, A preload)
//   C: bucket_gat (R15 verbatim)

constexpr int IN_F  = 256;
constexpr int F     = 128;   // OUT*HEADS
constexpr int HEADS = 8;
constexpr int BS    = 32;    // rows per fine bucket
constexpr int BSH   = 5;
constexpr int SLAB  = 2048;  // fine slab capacity (avg 1024, ~32 sigma)
constexpr int CSLAB = 9216;  // coarse slab capacity (avg 8192, ~11 sigma)
constexpr int PTILE = 4096;  // push1 tile size

typedef __attribute__((ext_vector_type(8))) short bf16x8;  // 8 bf16 in 4 VGPRs
typedef __attribute__((ext_vector_type(4))) float f32x4;

__device__ inline uint f2bf(float x) {              // f32 -> bf16 RNE (upper 16 bits)
    uint u = __float_as_uint(x);
    return (u + 0x7fffu + ((u >> 16) & 1u)) >> 16;
}
__device__ inline uint pack2(float a, float b) { return f2bf(a) | (f2bf(b) << 16); }

// ---------------- dispatch A: push1 (blocks < NPUSH) || prepack (rest) ----------
__global__ __launch_bounds__(256) void push1_prepack(
    const int* __restrict__ row, const int* __restrict__ col,
    int* __restrict__ ccnt, uint* __restrict__ cpairs, int E, int NPUSH,
    const float* __restrict__ W, uint4* __restrict__ Wf)
{
    __shared__ uint stage[PTILE];                   // 16 KB
    __shared__ int hist[256], st[256], cur[256], gbase[256];
    const int t = threadIdx.x;

    if (blockIdx.x >= NPUSH) {
        // ---- prepack: W -> MFMA B-fragment-linear bf16 ----
        int tt = (blockIdx.x - NPUSH) * 256 + t;
        if (tt >= 8 * 8 * 64) return;
        int ks = tt >> 9, nt = (tt >> 6) & 7, l = tt & 63;
        int c = nt * 16 + (l & 15);
        int k0 = ks * 32 + (l >> 4) * 8;
        float v[8];
#pragma unroll
        for (int i = 0; i < 8; ++i) v[i] = W[(size_t)(k0 + i) * F + c];
        Wf[tt] = make_uint4(pack2(v[0], v[1]), pack2(v[2], v[3]),
                            pack2(v[4], v[5]), pack2(v[6], v[7]));
        return;
    }

    // ---- push1: LDS tile-reorder scatter to coarse buckets (row>>8) ----
    const int i0 = blockIdx.x * PTILE;
    const int cnt = min(PTILE, E - i0);
    hist[t] = 0;
    __syncthreads();

    uint u[PTILE / 256];
#pragma unroll
    for (int j = 0; j < PTILE / 256; ++j) {
        const int idx = t + j * 256;
        if (idx < cnt) {
            int r = row[i0 + idx], c = col[i0 + idx];
            u[j] = ((uint)(r >> 8) << 24) | ((uint)c << 8) | (uint)(r & 255);
            atomicAdd(&hist[r >> 8], 1);
        } else u[j] = 0xFFFFFFFFu;
    }
    __syncthreads();

    const int v = hist[t];
    st[t] = v;
    __syncthreads();
    for (int off = 1; off < 256; off <<= 1) {
        int x = (t >= off) ? st[t - off] : 0;
        __syncthreads();
        st[t] += x;
        __syncthreads();
    }
    cur[t] = st[t] - v;                    // exclusive start within tile
    if (v) gbase[t] = t * CSLAB + atomicAdd(&ccnt[t], v);
    __syncthreads();

#pragma unroll
    for (int j = 0; j < PTILE / 256; ++j) {
        if (u[j] != 0xFFFFFFFFu) {
            int k = u[j] >> 24;
            int pos = atomicAdd(&cur[k], 1);
            stage[pos] = u[j];
        }
    }
    __syncthreads();

    for (int p = t; p < cnt; p += 256) {
        uint wv = stage[p];
        int k = wv >> 24;
        int lstart = st[k] - hist[k];
        __builtin_nontemporal_store(wv & 0xFFFFFFu, &cpairs[gbase[k] + (p - lstart)]);
    }
}

// ---------------- dispatch B: push2 (blocks < NC) || gemm (rest) ----------------
__global__ __launch_bounds__(256) void gemm_push2(
    const float* __restrict__ h, const uint4* __restrict__ Wf,
    const float* __restrict__ a_l, const float* __restrict__ a_r,
    uint* __restrict__ Whb, float* __restrict__ Wh1, float* __restrict__ Wh2,
    int n, int NC,
    const uint* __restrict__ cpairs, const int* __restrict__ ccnt,
    int* __restrict__ fcnt, uint* __restrict__ pairs)
{
    __shared__ int hl[8];
    __shared__ int cur8[8];
    const int tid = threadIdx.x;

    if (blockIdx.x < NC) {
        // ---- push2: coarse slab -> 8 fine slabs (dense both sides) ----
        const int c = blockIdx.x;
        const int p0 = c * CSLAB;
        const int ec = ccnt[c];
        if (tid < 8) hl[tid] = 0;
        __syncthreads();
        for (int p = tid; p < ec; p += 256)
            atomicAdd(&hl[(cpairs[p0 + p] >> 5) & 7], 1);
        __syncthreads();
        if (tid < 8)
            cur8[tid] = hl[tid] ? (c * 8 + tid) * SLAB + atomicAdd(&fcnt[c * 8 + tid], hl[tid]) : 0;
        __syncthreads();
        for (int p = tid; p < ec; p += 256) {
            uint u = cpairs[p0 + p];
            int pos = atomicAdd(&cur8[(u >> 5) & 7], 1);
            // coarse pair (col<<8)|(row&255) -> fine pair (col<<5)|(row&31)
            __builtin_nontemporal_store(((u >> 8) << 5) | (u & 31), &pairs[pos]);
        }
        return;
    }

    // ---- gemm body: full A preload (R12 proven) ----
    const int bid = blockIdx.x - NC;
    const int w = tid >> 6, l = tid & 63;
    const int r0 = bid * 64 + w * 16;
    const int rA = min(r0 + (l & 15), n - 1);       // A row (m = lane&15)
    const int kb = (l >> 4) * 8;                    // A k-subgroup

    const float* hp = &h[(size_t)rA * IN_F + kb];
    f32x4 af[16];
#pragma unroll
    for (int ks = 0; ks < 8; ++ks) {                // 16 loads, back-to-back
        af[2 * ks]     = __builtin_nontemporal_load((const f32x4*)(hp + ks * 32));
        af[2 * ks + 1] = __builtin_nontemporal_load((const f32x4*)(hp + ks * 32 + 4));
    }
    uint4 Abf[8];
#pragma unroll
    for (int ks = 0; ks < 8; ++ks) {
        f32x4 a0 = af[2 * ks], a1 = af[2 * ks + 1];
        Abf[ks] = make_uint4(pack2(a0[0], a0[1]), pack2(a0[2], a0[3]),
                             pack2(a1[0], a1[1]), pack2(a1[2], a1[3]));
    }

    f32x4 acc[8];
#pragma unroll
    for (int i = 0; i < 8; ++i) acc[i] = (f32x4)0.f;

#pragma unroll
    for (int ks = 0; ks < 8; ++ks) {
        union { uint4 u; bf16x8 v; } A;
        A.u = Abf[ks];
        const uint4* wp = &Wf[ks * 512 + l];
#pragma unroll
        for (int nt = 0; nt < 8; ++nt) {
            union { uint4 u; bf16x8 v; } B;
            B.u = wp[nt * 64];
            acc[nt] = __builtin_amdgcn_mfma_f32_16x16x32_bf16(A.v, B.v, acc[nt], 0, 0, 0);
        }
    }

    const int c16 = l & 15;
    const int rowm = r0 + 4 * (l >> 4);
    float al[8], ar[8];
#pragma unroll
    for (int H = 0; H < 8; ++H) {
        al[H] = a_l[H * 16 + c16];
        ar[H] = a_r[H * 16 + c16];
    }
#pragma unroll
    for (int reg = 0; reg < 4; ++reg) {
        const int r = rowm + reg;
        float s1v[8], s2v[8];
#pragma unroll
        for (int H = 0; H < 8; ++H) {
            float wv = acc[H][reg];
            s1v[H] = wv * al[H];
            s2v[H] = wv * ar[H];
        }
#pragma unroll
        for (int d = 1; d <= 8; d <<= 1) {
#pragma unroll
            for (int H = 0; H < 8; ++H) {
                s1v[H] += __shfl_xor(s1v[H], d);
                s2v[H] += __shfl_xor(s2v[H], d);
            }
        }
        if (r < n) {
#pragma unroll
            for (int nt = 0; nt < 4; ++nt)
                Whb[(size_t)r * 64 + nt * 16 + c16] = pack2(acc[nt][reg], acc[nt + 4][reg]);
            if (c16 == 0) {
                *(float4*)&Wh1[r * 8]     = make_float4(s1v[0], s1v[1], s1v[2], s1v[3]);
                *(float4*)&Wh1[r * 8 + 4] = make_float4(s1v[4], s1v[5], s1v[6], s1v[7]);
                *(float4*)&Wh2[r * 8]     = make_float4(s2v[0], s2v[1], s2v[2], s2v[3]);
                *(float4*)&Wh2[r * 8 + 4] = make_float4(s2v[4], s2v[5], s2v[6], s2v[7]);
            }
        }
    }
}

// ---------------- dispatch C: fused CSR-in-LDS + softmax + aggregate ------------
// R15 verbatim (pipelined ex; single-row k-loop).
__global__ __launch_bounds__(256) void bucket_gat(
    const uint* __restrict__ pairs, const int* __restrict__ fcnt,
    const uint* __restrict__ Whb, const float* __restrict__ Wh1,
    const float* __restrict__ Wh2, float* __restrict__ out, int n)
{
    __shared__ uint cols_l[SLAB];                   // 8 KB bucket col list
    __shared__ int cnt_l[BS], st0[BS], cur_l[BS];
    const int t = threadIdx.x;
    const int b = blockIdx.x;
    const int p0 = b * SLAB;
    const int ec = fcnt[b];                         // edges in this bucket

    if (t < BS) cnt_l[t] = 0;
    __syncthreads();
    for (int p = t; p < ec; p += 256)
        atomicAdd(&cnt_l[pairs[p0 + p] & (BS - 1)], 1);
    __syncthreads();
    if (t < BS) {
        int v = cnt_l[t];
        int inc = v;                                // inclusive scan over 32 lanes
#pragma unroll
        for (int off = 1; off < BS; off <<= 1) {
            int x = __shfl_up(inc, off);
            if (t >= off) inc += x;
        }
        st0[t] = inc - v;
        cur_l[t] = inc - v;
    }
    __syncthreads();
    for (int p = t; p < ec; p += 256) {
        uint u = pairs[p0 + p];
        int slot = atomicAdd(&cur_l[u & (BS - 1)], 1);
        cols_l[slot] = u >> BSH;
    }
    __syncthreads();

    const int wv = t >> 6, lane = t & 63;
    const int h8 = lane & 7, es = lane >> 3;
#pragma unroll 1
    for (int i = 0; i < 8; ++i) {
        const int rl = wv * 8 + i;
        const int r = (b << BSH) + rl;
        if (r >= n) continue;
        const float w1 = Wh1[r * HEADS + h8];
        const int st = st0[rl];
        const int deg = cnt_l[rl];
        if (deg == 0) {
            __builtin_nontemporal_store(0.f, &out[(size_t)r * F + lane]);
            __builtin_nontemporal_store(0.f, &out[(size_t)r * F + 64 + lane]);
            continue;
        }

        auto calc_ex = [&](int g) -> float {
            const int kk = g + es;
            const bool valid = kk < deg;
            const uint c = cols_l[st + (valid ? kk : deg - 1)];
            float e = w1 + Wh2[c * HEADS + h8];
            e = e > 0.f ? e : 0.2f * e;
            e = fminf(e, 60.f);                     // overflow guard
            return valid ? __expf(e) : 0.f;
        };

        float acc0 = 0.f, acc1 = 0.f, sm = 0.f;
        const int nfull8 = deg & ~7;                // full-group edge count
        float ex = calc_ex(0);                      // pipeline prologue

#pragma unroll 1
        for (int g = 0; g < nfull8; g += 8) {
            const float exn = (g + 8 < deg) ? calc_ex(g + 8) : 0.f;
            sm += ex;
#pragma unroll
            for (int k = 0; k < 8; ++k) {           // proven k-loop, verbatim
                float pA = __shfl(ex, k * 8 + h8);
                uint ck = cols_l[st + g + k];
                uint wb = Whb[((size_t)ck << 6) + lane];
                acc0 = fmaf(pA, __uint_as_float(wb << 16), acc0);
                acc1 = fmaf(pA, __uint_as_float(wb & 0xffff0000u), acc1);
            }
            ex = exn;
        }
        if (nfull8 < deg) {
            sm += ex;
            const int m8 = deg - nfull8;
            for (int k = 0; k < m8; ++k) {
                float pA = __shfl(ex, k * 8 + h8);
                uint ck = cols_l[st + nfull8 + k];
                uint wb = Whb[((size_t)ck << 6) + lane];
                acc0 = fmaf(pA, __uint_as_float(wb << 16), acc0);
                acc1 = fmaf(pA, __uint_as_float(wb & 0xffff0000u), acc1);
            }
        }

        sm += __shfl_xor(sm, 8);
        sm += __shfl_xor(sm, 16);
        sm += __shfl_xor(sm, 32);
        const float inv = 1.f / sm;
        __builtin_nontemporal_store(fmaxf(acc0 * inv, 0.f), &out[(size_t)r * F + lane]);
        __builtin_nontemporal_store(fmaxf(acc1 * inv, 0.f), &out[(size_t)r * F + 64 + lane]);
    }
}

// ---------------- launch ----------------
extern "C" void kernel_launch(void* const* d_in, const int* in_sizes, int n_in,
                              void* d_out, int out_size, void* d_ws, size_t ws_size,
                              hipStream_t stream)
{
    const int* row = (const int*)d_in[0];
    const int* col = (const int*)d_in[1];
    const float* h   = (const float*)d_in[2];
    const float* W   = (const float*)d_in[3];
    const float* a_l = (const float*)d_in[4];
    const float* a_r = (const float*)d_in[5];
    const int E = in_sizes[0];
    const int n = in_sizes[2] / IN_F;
    float* out = (float*)d_out;
    const int NBF = (n + BS - 1) >> BSH;                // fine buckets (1563)
    const int NC  = (n + 255) >> 8;                     // coarse buckets (196)
    const int NGEMM = (n + 63) / 64;
    const int NPUSH = (E + PTILE - 1) / PTILE;

    char* p = (char*)d_ws;
    auto alloc = [&](size_t bytes) -> char* {
        char* q = p;
        p += (bytes + 255) & ~(size_t)255;
        return q;
    };
    uint*  Whb    = (uint*)alloc((size_t)n * 64 * 4);   // paired bf16 cols (l, l+64)
    float* Wh1    = (float*)alloc((size_t)n * HEADS * 4);
    float* Wh2    = (float*)alloc((size_t)n * HEADS * 4);
    uint4* Wf     = (uint4*)alloc(8 * 8 * 64 * 16);     // prepacked W fragments
    int*   ccnt   = (int*)alloc((size_t)NC * 4);        // coarse bucket counts
    int*   fcnt   = (int*)alloc((size_t)NBF * 4);       // fine bucket counts
    uint*  cpairs = (uint*)alloc((size_t)NC * CSLAB * 4);
    uint*  pairs  = (uint*)alloc((size_t)NBF * SLAB * 4);

    hipMemsetAsync(ccnt, 0, (size_t)NC * 4, stream);
    hipMemsetAsync(fcnt, 0, (size_t)NBF * 4, stream);

    push1_prepack<<<NPUSH + 16, 256, 0, stream>>>(row, col, ccnt, cpairs, E, NPUSH, W, Wf);
    gemm_push2<<<NC + NGEMM, 256, 0, stream>>>(h, Wf, a_l, a_r, Whb, Wh1, Wh2,
                                               n, NC, cpairs, ccnt, fcnt, pairs);
    bucket_gat<<<NBF, 256, 0, stream>>>(pairs, fcnt, Whb, Wh1, Wh2, out, n);
}